// Round 2
// baseline (366.772 us; speedup 1.0000x reference)
//
#include <hip/hip_runtime.h>

// MaxUnpooling2D: out[b, mask[b,h,w,c]] = updates[b,h,w,c], rest zeros.
// B=16, H=W=64, C=256, OH=OW=128. mask: per-batch flat int32 index (verified
// round 1: absmax 0.0 reading int32). Indices unique -> plain stores.
//
// Round 1 lesson: hipMemsetAsync's fillBufferAligned ran at ~10% occupancy /
// 171 us, and 1-elem-per-thread scatter was issue-bound at ~180 us. Replace
// both with wide grid-stride kernels.

constexpr int B = 16;
constexpr int H = 64, W = 64, C = 256;
constexpr int IN_PER_BATCH  = H * W * C;              // 2^20
constexpr int OUT_PER_BATCH = (2 * H) * (2 * W) * C;  // 2^22
constexpr long long N_IN  = (long long)B * IN_PER_BATCH;   // 16,777,216
constexpr long long N_OUT = (long long)B * OUT_PER_BATCH;  // 67,108,864 floats

// ---- zero-fill: grid-stride float4 stores ----
__global__ void zero_fill_kernel(float4* __restrict__ out, long long n4) {
    long long stride = (long long)gridDim.x * blockDim.x;
    for (long long i = (long long)blockIdx.x * blockDim.x + threadIdx.x;
         i < n4; i += stride) {
        out[i] = make_float4(0.f, 0.f, 0.f, 0.f);
    }
}

// ---- scatter: 4 elems/thread, vector loads; vector store when indices are
//      consecutive & 16B-aligned (runtime-checked, honest fallback) ----
__global__ void unpool_scatter_kernel(const float4* __restrict__ updates4,
                                      const int4* __restrict__ mask4,
                                      float* __restrict__ out) {
    long long t = (long long)blockIdx.x * blockDim.x + threadIdx.x; // float4 idx
    if (t >= (N_IN >> 2)) return;
    int b = (int)(t >> 18);                  // (4*t) >> 20
    float* out_b = out + (long long)b * OUT_PER_BATCH;

    int4   m = mask4[t];
    float4 u = updates4[t];

    if (m.y == m.x + 1 && m.z == m.x + 2 && m.w == m.x + 3 && ((m.x & 3) == 0)) {
        *(float4*)(out_b + m.x) = u;         // fast path: one 16B store
    } else {
        out_b[m.x] = u.x;
        out_b[m.y] = u.y;
        out_b[m.z] = u.z;
        out_b[m.w] = u.w;
    }
}

extern "C" void kernel_launch(void* const* d_in, const int* in_sizes, int n_in,
                              void* d_out, int out_size, void* d_ws, size_t ws_size,
                              hipStream_t stream) {
    const float4* updates4 = (const float4*)d_in[0];
    const int4*   mask4    = (const int4*)d_in[1];
    float*        out      = (float*)d_out;

    // Zero-fill (output re-poisoned to 0xAA before every timed launch).
    const long long n4 = N_OUT >> 2;         // 16,777,216 float4s
    zero_fill_kernel<<<4096, 256, 0, stream>>>((float4*)out, n4);

    // Scatter.
    const long long nt = N_IN >> 2;          // 4,194,304 threads
    unpool_scatter_kernel<<<(int)((nt + 255) / 256), 256, 0, stream>>>(
        updates4, mask4, out);
}

// Round 3
// 358.771 us; speedup vs baseline: 1.0223x; 1.0223x over previous
//
#include <hip/hip_runtime.h>

// MaxUnpooling2D fused gather formulation.
// B=16, H=W=64, C=256, OH=OW=128. mask: per-batch flat int32 index.
//
// Round 2 lesson: the ~165us 1-GiB fillBufferAligned dispatches in the profile
// are the HARNESS's 0xAA re-poison of d_out/d_ws (they persisted after I
// removed my hipMemsetAsync) — a fixed ~230us floor inside the measured
// window. Only my kernel time (~130us in R2) is controllable.
//
// Fusion: max_pool_with_argmax structure guarantees each mask index points
// inside its own 2x2 window, same channel & batch. Therefore output position
// (b, 2h+dh, 2w+dw, c) has exactly one candidate source: updates[b,h,w,c],
// taken iff mask[b,h,w,c] == flat(2h+dh, 2w+dw, c). Each thread owns one
// input quad (b,h,w,c*4), reads mask4+updates4 once, writes the 4 window
// positions (select u or 0). Every output element written exactly once ->
// zero-fill pass eliminated entirely.
//
// Traffic: 64MB updates + 64MB mask read, 268MB write, ONE dispatch (~63us
// at 6.3 TB/s) vs 448MB + two dispatches for zero+scatter.

constexpr int B = 16;
constexpr int H = 64, W = 64, C = 256;
constexpr int OW = 2 * W;                              // 128
constexpr int OUT_PER_BATCH = (2 * H) * OW * C;        // 2^22
constexpr long long N_THREADS = (long long)B * H * W * (C / 4); // 4,194,304

__global__ __launch_bounds__(256) void unpool_gather_kernel(
    const float4* __restrict__ updates4,
    const int4*   __restrict__ mask4,
    float*        __restrict__ out) {
    int t = blockIdx.x * blockDim.x + threadIdx.x;   // < 2^22, fits int
    // t -> (b, h, w, c4); identical linear layout to updates4/mask4.
    int c4 = t & 63;          // C/4 = 64 quads
    int w  = (t >> 6) & 63;
    int h  = (t >> 12) & 63;
    int b  = t >> 18;

    int4   m = mask4[t];
    float4 u = updates4[t];

    // Flat index of (2h, 2w, 4*c4) in [OH, OW, C] — also the base store offset.
    int base00 = ((h << 1) * OW + (w << 1)) * C + (c4 << 2);
    float* out_b = out + (long long)b * OUT_PER_BATCH;

    const int ROW = OW * C;   // 32768
    #pragma unroll
    for (int j = 0; j < 4; ++j) {
        int off = ((j >> 1) ? ROW : 0) + ((j & 1) ? C : 0);
        int tgt = base00 + off;
        float4 v;
        v.x = (m.x == tgt + 0) ? u.x : 0.0f;
        v.y = (m.y == tgt + 1) ? u.y : 0.0f;
        v.z = (m.z == tgt + 2) ? u.z : 0.0f;
        v.w = (m.w == tgt + 3) ? u.w : 0.0f;
        *(float4*)(out_b + tgt) = v;
    }
}

extern "C" void kernel_launch(void* const* d_in, const int* in_sizes, int n_in,
                              void* d_out, int out_size, void* d_ws, size_t ws_size,
                              hipStream_t stream) {
    const float4* updates4 = (const float4*)d_in[0];
    const int4*   mask4    = (const int4*)d_in[1];
    float*        out      = (float*)d_out;

    const int block = 256;
    const int grid  = (int)(N_THREADS / block);      // 16384 blocks
    unpool_gather_kernel<<<grid, block, 0, stream>>>(updates4, mask4, out);
}